// Round 3
// baseline (333.956 us; speedup 1.0000x reference)
//
#include <hip/hip_runtime.h>
#include <math.h>

// Dims: B=16, H=64, W=64, Cin=3, F=32, K=3
// Conv strategy: 1-wave (64-thread) blocks; filter-group comes from blockIdx
// (=> SGPR by construction), weights laid out [c4][tap][cc][f32] so every
// (tap,cc) row is a contiguous scalar-addressed chunk -> s_load_dwordx8.
// Inputs double-buffered in registers (static indexing), FMAs on VALU fp32.

__device__ float g_wT[9216];  // [(c4*9 + tap)*4 + cc][f=32]

__device__ __forceinline__ float f4c(const float4 v, int cc) {
  return cc == 0 ? v.x : cc == 1 ? v.y : cc == 2 ? v.z : v.w;
}

// -------- transpose wsh [f=32][k=tap*32+c] -> g_wT [(c4*9+tap)*4+cc][f] -----
__global__ __launch_bounds__(256) void transpose_w(const float* __restrict__ w) {
  const int idx = threadIdx.x + blockIdx.x * 256;
  if (idx < 9216) {
    const int f = idx / 288;
    const int k = idx - f * 288;
    const int tap = k >> 5;
    const int c = k & 31;
    const int c4 = c >> 2;
    const int cc = c & 3;
    g_wT[(((c4 * 9 + tap) * 4) + cc) * 32 + f] = w[idx];
  }
}

// ---------------- conv0: Cin=3 -> F=32, W0 is HWIO [tap][c][f] --------------
__global__ __launch_bounds__(256) void conv0_relu(
    const float* __restrict__ in, const float* __restrict__ W0,
    const float* __restrict__ b0, float* __restrict__ out) {
  const int p = blockIdx.x * 256 + threadIdx.x;
  const int b = p >> 12;
  const int rem = p & 4095;
  const int h = rem >> 6;
  const int w = rem & 63;

  float iv[3][3][3];  // [row][col][c]
#pragma unroll
  for (int r = 0; r < 3; ++r) {
    const int hh = h - 1 + r;
    const bool vr = (unsigned)hh < 64u;
#pragma unroll
    for (int j = 0; j < 3; ++j) {
      const int col = w - 1 + j;
      const bool ok = vr && ((unsigned)col < 64u);
      const float* ip = in + (((b << 6) + hh) * 64 + col) * 3;
      iv[r][j][0] = ok ? ip[0] : 0.f;
      iv[r][j][1] = ok ? ip[1] : 0.f;
      iv[r][j][2] = ok ? ip[2] : 0.f;
    }
  }

  float acc[32];
#pragma unroll
  for (int f = 0; f < 32; ++f) acc[f] = 0.f;

#pragma unroll
  for (int dy = 0; dy < 3; ++dy) {
#pragma unroll
    for (int dx = 0; dx < 3; ++dx) {
#pragma unroll
      for (int c = 0; c < 3; ++c) {
        const float ival = iv[dy][dx][c];
        const float* wp = W0 + (((dy * 3 + dx) * 3) + c) * 32;  // uniform -> s_load
#pragma unroll
        for (int f = 0; f < 32; ++f) acc[f] += ival * wp[f];
      }
    }
  }

  float* op = out + p * 32;
#pragma unroll
  for (int f4 = 0; f4 < 8; ++f4) {
    float4 r;
    r.x = fmaxf(acc[f4 * 4 + 0] + b0[f4 * 4 + 0], 0.f);
    r.y = fmaxf(acc[f4 * 4 + 1] + b0[f4 * 4 + 1], 0.f);
    r.z = fmaxf(acc[f4 * 4 + 2] + b0[f4 * 4 + 2], 0.f);
    r.w = fmaxf(acc[f4 * 4 + 3] + b0[f4 * 4 + 3], 0.f);
    *(float4*)(op + f4 * 4) = r;
  }
}

// ---------------- shared conv 32->32, scalar-pipe weights -------------------
template <int H, int W, int P, int NC>
__device__ __forceinline__ void loadq(float4 (&v)[3][NC], const float* __restrict__ in,
                                      int b, int h, int w, int c4) {
#pragma unroll
  for (int r = 0; r < 3; ++r) {
    const int hh = h - 1 + r;
    const bool vr = (unsigned)hh < (unsigned)H;
    const float* rp = in + ((b * H + hh) * W) * 32 + c4 * 4;
#pragma unroll
    for (int j = 0; j < NC; ++j) {
      const int col = w - 1 + j;
      const bool ok = vr && ((unsigned)col < (unsigned)W);
      v[r][j] = ok ? *(const float4*)(rp + col * 32) : float4{0.f, 0.f, 0.f, 0.f};
    }
  }
}

template <int P, int NF, int NC>
__device__ __forceinline__ void fmaq(float (&acc)[P][NF], const float4 (&v)[3][NC],
                                     const float* __restrict__ wfg, int c4) {
#pragma unroll
  for (int tap = 0; tap < 9; ++tap) {
    const int dy = tap / 3;
    const int dx = tap - dy * 3;
#pragma unroll
    for (int cc = 0; cc < 4; ++cc) {
      // wfg is scalar (blockIdx-derived); contiguous NF floats -> s_load
      const float* wr = wfg + ((c4 * 9 + tap) * 4 + cc) * 32;
#pragma unroll
      for (int f = 0; f < NF; ++f) {
        const float wv = wr[f];
#pragma unroll
        for (int p = 0; p < P; ++p) acc[p][f] += f4c(v[dy][p + dx], cc) * wv;
      }
    }
  }
}

template <int H, int W, int P, int NF, int LGFG>
__global__ __launch_bounds__(64) void conv_sh3(
    const float* __restrict__ in, const float* __restrict__ bsh,
    float* __restrict__ out) {
  constexpr int FG = 1 << LGFG;
  constexpr int NC = P + 2;
  const int fg = blockIdx.x & (FG - 1);   // SGPR by construction
  const int pg = blockIdx.x >> LGFG;
  const int lane = threadIdx.x;
  const int pxbase = (pg * 64 + lane) * P;
  const int b = pxbase / (H * W);
  const int rem = pxbase - b * (H * W);
  const int h = rem / W;
  const int w = rem - h * W;  // P | W so w..w+P-1 stay in this row

  const float* wfg = g_wT + fg * NF;

  float acc[P][NF];
#pragma unroll
  for (int p = 0; p < P; ++p)
#pragma unroll
    for (int f = 0; f < NF; ++f) acc[p][f] = 0.f;

  float4 vA[3][NC], vB[3][NC];
  loadq<H, W, P, NC>(vA, in, b, h, w, 0);
#pragma unroll 1
  for (int c4 = 0; c4 < 8; c4 += 2) {
    loadq<H, W, P, NC>(vB, in, b, h, w, c4 + 1);
    fmaq<P, NF, NC>(acc, vA, wfg, c4);
    if (c4 + 2 < 8) loadq<H, W, P, NC>(vA, in, b, h, w, c4 + 2);
    fmaq<P, NF, NC>(acc, vB, wfg, c4 + 1);
  }

#pragma unroll
  for (int p = 0; p < P; ++p) {
    float* op = out + (pxbase + p) * 32 + fg * NF;
#pragma unroll
    for (int f4 = 0; f4 < NF / 4; ++f4) {
      float4 r;
      r.x = fmaxf(acc[p][f4 * 4 + 0] + bsh[fg * NF + f4 * 4 + 0], 0.f);
      r.y = fmaxf(acc[p][f4 * 4 + 1] + bsh[fg * NF + f4 * 4 + 1], 0.f);
      r.z = fmaxf(acc[p][f4 * 4 + 2] + bsh[fg * NF + f4 * 4 + 2], 0.f);
      r.w = fmaxf(acc[p][f4 * 4 + 3] + bsh[fg * NF + f4 * 4 + 3], 0.f);
      *(float4*)(op + f4 * 4) = r;
    }
  }
}

// ---------------- 2x2 maxpool stride 2, NHWC, C=32 --------------------------
template <int HO, int WO, int LGW, int LGH>
__global__ __launch_bounds__(256) void maxpool2(const float* __restrict__ in,
                                                float* __restrict__ out) {
  const int idx = blockIdx.x * 256 + threadIdx.x;  // float4 index
  const int f4 = idx & 7;
  const int r = idx >> 3;
  const int wo = r & (WO - 1);
  const int r2 = r >> LGW;
  const int ho = r2 & (HO - 1);
  const int b = r2 >> LGH;
  const int Win = WO * 2;
  const float* p00 = in + (((b * 2 * HO + 2 * ho) * Win) + 2 * wo) * 32 + f4 * 4;
  const float4 a = *(const float4*)p00;
  const float4 bb = *(const float4*)(p00 + 32);
  const float4 c = *(const float4*)(p00 + Win * 32);
  const float4 d = *(const float4*)(p00 + Win * 32 + 32);
  float4 m;
  m.x = fmaxf(fmaxf(a.x, bb.x), fmaxf(c.x, d.x));
  m.y = fmaxf(fmaxf(a.y, bb.y), fmaxf(c.y, d.y));
  m.z = fmaxf(fmaxf(a.z, bb.z), fmaxf(c.z, d.z));
  m.w = fmaxf(fmaxf(a.w, bb.w), fmaxf(c.w, d.w));
  *(float4*)(out + ((b * HO + ho) * WO + wo) * 32 + f4 * 4) = m;
}

// ---------------- dense 8192->10 + softmax, one block per batch row ---------
__global__ __launch_bounds__(256) void dense_softmax(
    const float* __restrict__ x, const float* __restrict__ Wd,
    const float* __restrict__ bd, float* __restrict__ out) {
  const int b = blockIdx.x;
  const int tid = threadIdx.x;
  const float* xb = x + b * 8192;
  float acc[10];
#pragma unroll
  for (int j = 0; j < 10; ++j) acc[j] = 0.f;
  for (int i = tid; i < 8192; i += 256) {
    const float xv = xb[i];
    const float* wr = Wd + i * 10;
#pragma unroll
    for (int j = 0; j < 10; ++j) acc[j] += xv * wr[j];
  }
  __shared__ float red[10 * 256];
#pragma unroll
  for (int j = 0; j < 10; ++j) red[j * 256 + tid] = acc[j];
  __syncthreads();
  for (int s = 128; s > 0; s >>= 1) {
    if (tid < s) {
#pragma unroll
      for (int j = 0; j < 10; ++j) red[j * 256 + tid] += red[j * 256 + tid + s];
    }
    __syncthreads();
  }
  if (tid == 0) {
    float lg[10];
    float m = -1e30f;
#pragma unroll
    for (int j = 0; j < 10; ++j) {
      lg[j] = red[j * 256] + bd[j];
      m = fmaxf(m, lg[j]);
    }
    float s = 0.f;
#pragma unroll
    for (int j = 0; j < 10; ++j) {
      lg[j] = expf(lg[j] - m);
      s += lg[j];
    }
    const float inv = 1.f / s;
#pragma unroll
    for (int j = 0; j < 10; ++j) out[b * 10 + j] = lg[j] * inv;
  }
}

extern "C" void kernel_launch(void* const* d_in, const int* in_sizes, int n_in,
                              void* d_out, int out_size, void* d_ws, size_t ws_size,
                              hipStream_t stream) {
  const float* in = (const float*)d_in[0];
  const float* W0 = (const float*)d_in[1];
  const float* b0 = (const float*)d_in[2];
  const float* wsh = (const float*)d_in[3];
  const float* bsh = (const float*)d_in[4];
  const float* Wd = (const float*)d_in[5];
  const float* bd = (const float*)d_in[6];
  float* out = (float*)d_out;

  float* A = (float*)d_ws;           // 16*64*64*32 floats (8 MB)
  float* B = A + 16 * 64 * 64 * 32;  // second 8 MB buffer

  transpose_w<<<36, 256, 0, stream>>>(wsh);
  conv0_relu<<<256, 256, 0, stream>>>(in, W0, b0, A);
  // 64x64 convs: FG=4 filter-groups of 8, P=2 pixels/thread -> 2048 blocks
  conv_sh3<64, 64, 2, 8, 2><<<2048, 64, 0, stream>>>(A, bsh, B);
  conv_sh3<64, 64, 2, 8, 2><<<2048, 64, 0, stream>>>(B, bsh, A);
  maxpool2<32, 32, 5, 5><<<512, 256, 0, stream>>>(A, B);  // 64x64 -> 32x32
  // 32x32 convs: FG=8 filter-groups of 4, P=1 -> 2048 blocks
  conv_sh3<32, 32, 1, 4, 3><<<2048, 64, 0, stream>>>(B, bsh, A);
  conv_sh3<32, 32, 1, 4, 3><<<2048, 64, 0, stream>>>(A, bsh, B);
  maxpool2<16, 16, 4, 4><<<128, 256, 0, stream>>>(B, A);  // 32x32 -> 16x16
  dense_softmax<<<16, 256, 0, stream>>>(A, Wd, bd, out);
}

// Round 4
// 183.009 us; speedup vs baseline: 1.8248x; 1.8248x over previous
//
#include <hip/hip_runtime.h>
#include <math.h>

// Dims: B=16, H=64, W=64, Cin=3, F=32, K=3
// Conv strategy: 256/512-thread blocks where ALL waves cover the SAME
// contiguous pixel strip (L1-friendly, one input read total); each wave owns a
// filter-group fg = readfirstlane(waveid) -> SGPR by construction -> weight
// loads are s_load_dwordx8 on the scalar pipe (zero VALU/VMEM/LDS cost).
// Weights pre-transposed into per-fg contiguous blocks (scalar-cache-resident).
// Inputs register-double-buffered across channel quads.

__device__ float g_wT8[9216];  // [fg=4][c4=8][tap=9][cc=4][f=8]
__device__ float g_wT4[9216];  // [fg=8][c4=8][tap=9][cc=4][f=4]

__device__ __forceinline__ float f4c(const float4 v, int cc) {
  return cc == 0 ? v.x : cc == 1 ? v.y : cc == 2 ? v.z : v.w;
}

// -------- transpose wsh [f=32][k=tap*32+c] into both per-fg layouts ---------
__global__ __launch_bounds__(256) void transpose_w(const float* __restrict__ w) {
  const int idx = threadIdx.x + blockIdx.x * 256;
  if (idx < 9216) {
    const int f = idx / 288;
    const int k = idx - f * 288;
    const int tap = k >> 5;
    const int c = k & 31;
    const int c4 = c >> 2;
    const int cc = c & 3;
    const float v = w[idx];
    g_wT8[(((((f >> 3) * 8) + c4) * 9 + tap) * 4 + cc) * 8 + (f & 7)] = v;
    g_wT4[(((((f >> 2) * 8) + c4) * 9 + tap) * 4 + cc) * 4 + (f & 3)] = v;
  }
}

// ---------------- conv0: Cin=3 -> F=32, W0 is HWIO [tap][c][f] --------------
__global__ __launch_bounds__(256) void conv0_relu(
    const float* __restrict__ in, const float* __restrict__ W0,
    const float* __restrict__ b0, float* __restrict__ out) {
  const int p = blockIdx.x * 256 + threadIdx.x;
  const int b = p >> 12;
  const int rem = p & 4095;
  const int h = rem >> 6;
  const int w = rem & 63;

  float iv[3][3][3];  // [row][col][c]
#pragma unroll
  for (int r = 0; r < 3; ++r) {
    const int hh = h - 1 + r;
    const bool vr = (unsigned)hh < 64u;
#pragma unroll
    for (int j = 0; j < 3; ++j) {
      const int col = w - 1 + j;
      const bool ok = vr && ((unsigned)col < 64u);
      const float* ip = in + (((b << 6) + hh) * 64 + col) * 3;
      iv[r][j][0] = ok ? ip[0] : 0.f;
      iv[r][j][1] = ok ? ip[1] : 0.f;
      iv[r][j][2] = ok ? ip[2] : 0.f;
    }
  }

  float acc[32];
#pragma unroll
  for (int f = 0; f < 32; ++f) acc[f] = 0.f;

#pragma unroll
  for (int dy = 0; dy < 3; ++dy) {
#pragma unroll
    for (int dx = 0; dx < 3; ++dx) {
#pragma unroll
      for (int c = 0; c < 3; ++c) {
        const float ival = iv[dy][dx][c];
        const float* wp = W0 + (((dy * 3 + dx) * 3) + c) * 32;  // uniform -> s_load
#pragma unroll
        for (int f = 0; f < 32; ++f) acc[f] += ival * wp[f];
      }
    }
  }

  float* op = out + p * 32;
#pragma unroll
  for (int f4 = 0; f4 < 8; ++f4) {
    float4 r;
    r.x = fmaxf(acc[f4 * 4 + 0] + b0[f4 * 4 + 0], 0.f);
    r.y = fmaxf(acc[f4 * 4 + 1] + b0[f4 * 4 + 1], 0.f);
    r.z = fmaxf(acc[f4 * 4 + 2] + b0[f4 * 4 + 2], 0.f);
    r.w = fmaxf(acc[f4 * 4 + 3] + b0[f4 * 4 + 3], 0.f);
    *(float4*)(op + f4 * 4) = r;
  }
}

// ---------------- shared conv 32->32, scalar-pipe weights -------------------
template <int H, int W, int P, int NC>
__device__ __forceinline__ void loadq(float4 (&v)[3][NC], const float* __restrict__ in,
                                      int b, int h, int w, int c4) {
#pragma unroll
  for (int r = 0; r < 3; ++r) {
    const int hh = h - 1 + r;
    const bool vr = (unsigned)hh < (unsigned)H;
    const float* rp = in + ((b * H + hh) * W) * 32 + c4 * 4;
#pragma unroll
    for (int j = 0; j < NC; ++j) {
      const int col = w - 1 + j;
      const bool ok = vr && ((unsigned)col < (unsigned)W);
      v[r][j] = ok ? *(const float4*)(rp + col * 32) : float4{0.f, 0.f, 0.f, 0.f};
    }
  }
}

template <int P, int NF, int NC>
__device__ __forceinline__ void fmaq(float (&acc)[P][NF], const float4 (&v)[3][NC],
                                     const float* __restrict__ wfg, int c4) {
#pragma unroll
  for (int tap = 0; tap < 9; ++tap) {
    const int dy = tap / 3;
    const int dx = tap - dy * 3;
#pragma unroll
    for (int cc = 0; cc < 4; ++cc) {
      // wfg is SGPR-based (readfirstlane fg) -> these are s_load (scalar pipe)
      const float* wr = wfg + ((c4 * 9 + tap) * 4 + cc) * NF;
#pragma unroll
      for (int f = 0; f < NF; ++f) {
        const float wv = wr[f];
#pragma unroll
        for (int p = 0; p < P; ++p) acc[p][f] += f4c(v[dy][p + dx], cc) * wv;
      }
    }
  }
}

template <int H, int W, int P, int NF>
__global__ __launch_bounds__(64 * (32 / NF)) void conv_sh4(
    const float* __restrict__ in, const float* __restrict__ wT,
    const float* __restrict__ bsh, float* __restrict__ out) {
  constexpr int NC = P + 2;
  // wave id -> filter group, certified wave-uniform => SGPR
  const int fg = __builtin_amdgcn_readfirstlane((int)(threadIdx.x >> 6));
  const int lane = threadIdx.x & 63;
  const int pxbase = blockIdx.x * (64 * P) + lane * P;  // contiguous strip/block
  const int b = pxbase / (H * W);
  const int rem = pxbase - b * (H * W);
  const int h = rem / W;
  const int w = rem - h * W;  // P | W so w..w+P-1 stay in this row

  const float* wfg = wT + fg * (8 * 9 * 4 * NF);  // per-fg contiguous block

  float acc[P][NF];
#pragma unroll
  for (int p = 0; p < P; ++p)
#pragma unroll
    for (int f = 0; f < NF; ++f) acc[p][f] = 0.f;

  float4 vA[3][NC], vB[3][NC];
  loadq<H, W, P, NC>(vA, in, b, h, w, 0);
#pragma unroll 1
  for (int c4 = 0; c4 < 8; c4 += 2) {
    loadq<H, W, P, NC>(vB, in, b, h, w, c4 + 1);
    fmaq<P, NF, NC>(acc, vA, wfg, c4);
    if (c4 + 2 < 8) loadq<H, W, P, NC>(vA, in, b, h, w, c4 + 2);
    fmaq<P, NF, NC>(acc, vB, wfg, c4 + 1);
  }

#pragma unroll
  for (int p = 0; p < P; ++p) {
    float* op = out + (pxbase + p) * 32 + fg * NF;
#pragma unroll
    for (int f4 = 0; f4 < NF / 4; ++f4) {
      float4 r;
      r.x = fmaxf(acc[p][f4 * 4 + 0] + bsh[fg * NF + f4 * 4 + 0], 0.f);
      r.y = fmaxf(acc[p][f4 * 4 + 1] + bsh[fg * NF + f4 * 4 + 1], 0.f);
      r.z = fmaxf(acc[p][f4 * 4 + 2] + bsh[fg * NF + f4 * 4 + 2], 0.f);
      r.w = fmaxf(acc[p][f4 * 4 + 3] + bsh[fg * NF + f4 * 4 + 3], 0.f);
      *(float4*)(op + f4 * 4) = r;
    }
  }
}

// ---------------- 2x2 maxpool stride 2, NHWC, C=32 --------------------------
template <int HO, int WO, int LGW, int LGH>
__global__ __launch_bounds__(256) void maxpool2(const float* __restrict__ in,
                                                float* __restrict__ out) {
  const int idx = blockIdx.x * 256 + threadIdx.x;  // float4 index
  const int f4 = idx & 7;
  const int r = idx >> 3;
  const int wo = r & (WO - 1);
  const int r2 = r >> LGW;
  const int ho = r2 & (HO - 1);
  const int b = r2 >> LGH;
  const int Win = WO * 2;
  const float* p00 = in + (((b * 2 * HO + 2 * ho) * Win) + 2 * wo) * 32 + f4 * 4;
  const float4 a = *(const float4*)p00;
  const float4 bb = *(const float4*)(p00 + 32);
  const float4 c = *(const float4*)(p00 + Win * 32);
  const float4 d = *(const float4*)(p00 + Win * 32 + 32);
  float4 m;
  m.x = fmaxf(fmaxf(a.x, bb.x), fmaxf(c.x, d.x));
  m.y = fmaxf(fmaxf(a.y, bb.y), fmaxf(c.y, d.y));
  m.z = fmaxf(fmaxf(a.z, bb.z), fmaxf(c.z, d.z));
  m.w = fmaxf(fmaxf(a.w, bb.w), fmaxf(c.w, d.w));
  *(float4*)(out + ((b * HO + ho) * WO + wo) * 32 + f4 * 4) = m;
}

// ---------------- dense 8192->10 + softmax, one block per batch row ---------
__global__ __launch_bounds__(256) void dense_softmax(
    const float* __restrict__ x, const float* __restrict__ Wd,
    const float* __restrict__ bd, float* __restrict__ out) {
  const int b = blockIdx.x;
  const int tid = threadIdx.x;
  const float* xb = x + b * 8192;
  float acc[10];
#pragma unroll
  for (int j = 0; j < 10; ++j) acc[j] = 0.f;
  for (int i = tid; i < 8192; i += 256) {
    const float xv = xb[i];
    const float* wr = Wd + i * 10;
#pragma unroll
    for (int j = 0; j < 10; ++j) acc[j] += xv * wr[j];
  }
  __shared__ float red[10 * 256];
#pragma unroll
  for (int j = 0; j < 10; ++j) red[j * 256 + tid] = acc[j];
  __syncthreads();
  for (int s = 128; s > 0; s >>= 1) {
    if (tid < s) {
#pragma unroll
      for (int j = 0; j < 10; ++j) red[j * 256 + tid] += red[j * 256 + tid + s];
    }
    __syncthreads();
  }
  if (tid == 0) {
    float lg[10];
    float m = -1e30f;
#pragma unroll
    for (int j = 0; j < 10; ++j) {
      lg[j] = red[j * 256] + bd[j];
      m = fmaxf(m, lg[j]);
    }
    float s = 0.f;
#pragma unroll
    for (int j = 0; j < 10; ++j) {
      lg[j] = expf(lg[j] - m);
      s += lg[j];
    }
    const float inv = 1.f / s;
#pragma unroll
    for (int j = 0; j < 10; ++j) out[b * 10 + j] = lg[j] * inv;
  }
}

extern "C" void kernel_launch(void* const* d_in, const int* in_sizes, int n_in,
                              void* d_out, int out_size, void* d_ws, size_t ws_size,
                              hipStream_t stream) {
  const float* in = (const float*)d_in[0];
  const float* W0 = (const float*)d_in[1];
  const float* b0 = (const float*)d_in[2];
  const float* wsh = (const float*)d_in[3];
  const float* bsh = (const float*)d_in[4];
  const float* Wd = (const float*)d_in[5];
  const float* bd = (const float*)d_in[6];
  float* out = (float*)d_out;

  float* A = (float*)d_ws;           // 16*64*64*32 floats (8 MB)
  float* B = A + 16 * 64 * 64 * 32;  // second 8 MB buffer

  float* wT8;
  float* wT4;
  hipGetSymbolAddress((void**)&wT8, HIP_SYMBOL(g_wT8));
  hipGetSymbolAddress((void**)&wT4, HIP_SYMBOL(g_wT4));

  transpose_w<<<36, 256, 0, stream>>>(wsh);
  conv0_relu<<<256, 256, 0, stream>>>(in, W0, b0, A);
  // 64x64 convs: blocks of 4 waves (fg 0..3, NF=8), P=2 -> 512 blocks
  conv_sh4<64, 64, 2, 8><<<512, 256, 0, stream>>>(A, wT8, bsh, B);
  conv_sh4<64, 64, 2, 8><<<512, 256, 0, stream>>>(B, wT8, bsh, A);
  maxpool2<32, 32, 5, 5><<<512, 256, 0, stream>>>(A, B);  // 64x64 -> 32x32
  // 32x32 convs: blocks of 8 waves (fg 0..7, NF=4), P=1 -> 256 blocks
  conv_sh4<32, 32, 1, 4><<<256, 512, 0, stream>>>(B, wT4, bsh, A);
  conv_sh4<32, 32, 1, 4><<<256, 512, 0, stream>>>(A, wT4, bsh, B);
  maxpool2<16, 16, 4, 4><<<128, 256, 0, stream>>>(B, A);  // 32x32 -> 16x16
  dense_softmax<<<16, 256, 0, stream>>>(A, Wd, bd, out);
}